// Round 17
// baseline (10886.044 us; speedup 1.0000x reference)
//
#include <hip/hip_runtime.h>

#define NB 256      // 16 cohorts x 16 slice-blocks
#define BT 512
#define BB 64
#define TT 1024
#define LL 400
#define EE 512
#define DD 80
#define AA 512
#define KK 5

// ws float offsets
#define WF_HB 2048                    // [64][512] hout exchange
#define WF_PP 34816                   // [3][64][16] param partial accumulators
#define WF_PL 51200                   // [3][64][320] lstm1 partial accumulators
#define WF_EW 112640                  // [64][1024][320] enc@Wx1 (optional)
#define WF_EWSZ (64UL*1024UL*320UL)

struct Pr {
  const float *enc;
  const float *pW1,*pb1,*pW2,*pb2;
  const float *gWx,*gWh,*gbx,*gbh;
  const float *aW1,*ab1,*aW2,*ab2;
  const float *lWx1,*lWh1,*lb1,*lWx2,*lWh2,*lb2;
  const float *sW,*sb;
  float *oa,*obf,*ol;
  unsigned *ctr;
  float *hb,*pp,*pls,*ew;
  int useEW;
};

__device__ __forceinline__ float sigm(float x){ return 1.f/(1.f+expf(-x)); }
__device__ __forceinline__ float softplusf(float x){ return fmaxf(x,0.f)+log1pf(expf(-fabsf(x))); }
__device__ __forceinline__ void gstore(float* p, float v){
  __hip_atomic_store(p, v, __ATOMIC_RELAXED, __HIP_MEMORY_SCOPE_AGENT);
}
__device__ __forceinline__ float gload(const float* p){
  return __hip_atomic_load(p, __ATOMIC_RELAXED, __HIP_MEMORY_SCOPE_AGENT);
}
__device__ __forceinline__ void gadd(float* p, float v){
  __hip_atomic_fetch_add(p, v, __ATOMIC_RELAXED, __HIP_MEMORY_SCOPE_AGENT);
}
__device__ __forceinline__ void acc4(float4& a, float w, const float4 x){
  a.x = fmaf(w,x.x,a.x); a.y = fmaf(w,x.y,a.y);
  a.z = fmaf(w,x.z,a.z); a.w = fmaf(w,x.w,a.w);
}

// 16-block cohort barrier, split arrive/wait (fence-free; proven r5-r16)
__device__ __forceinline__ void cbar_arrive(unsigned* ctr){
  __syncthreads();
  if (threadIdx.x == 0){
    asm volatile("s_waitcnt vmcnt(0)" ::: "memory");
    __hip_atomic_fetch_add(ctr, 1u, __ATOMIC_RELAXED, __HIP_MEMORY_SCOPE_AGENT);
  }
}
__device__ __forceinline__ void cbar_wait(unsigned* ctr, unsigned& tgt){
  if (threadIdx.x == 0){
    while (__hip_atomic_load(ctr, __ATOMIC_RELAXED, __HIP_MEMORY_SCOPE_AGENT) < tgt)
      __builtin_amdgcn_s_sleep(1);
  }
  __syncthreads();
  tgt += 16;
}

// one-time EW[b][t][col] = sum_e enc[b][t][e] * lWx1[e][col]
__global__ __launch_bounds__(512) void ew_kernel(const float* __restrict__ enc,
                                                 const float* __restrict__ W,
                                                 float* __restrict__ EW){
  const int b = blockIdx.x, t0 = blockIdx.y*16, tid = threadIdx.x;
  __shared__ float encT[512*16];
  #pragma unroll
  for (int r=0;r<16;++r)
    encT[tid*16+r] = enc[((size_t)b*TT + t0 + r)*EE + tid];
  __syncthreads();
  if (tid < 320){
    float acc[16];
    #pragma unroll
    for (int k=0;k<16;++k) acc[k]=0.f;
    const float* wp = W + tid;
    #pragma unroll 2
    for (int e=0;e<512;++e){
      float w = wp[(size_t)e*320];
      const float4* er = (const float4*)&encT[e*16];
      float4 x0=er[0], x1=er[1], x2=er[2], x3=er[3];
      acc[0]=fmaf(w,x0.x,acc[0]); acc[1]=fmaf(w,x0.y,acc[1]);
      acc[2]=fmaf(w,x0.z,acc[2]); acc[3]=fmaf(w,x0.w,acc[3]);
      acc[4]=fmaf(w,x1.x,acc[4]); acc[5]=fmaf(w,x1.y,acc[5]);
      acc[6]=fmaf(w,x1.z,acc[6]); acc[7]=fmaf(w,x1.w,acc[7]);
      acc[8]=fmaf(w,x2.x,acc[8]); acc[9]=fmaf(w,x2.y,acc[9]);
      acc[10]=fmaf(w,x2.z,acc[10]); acc[11]=fmaf(w,x2.w,acc[11]);
      acc[12]=fmaf(w,x3.x,acc[12]); acc[13]=fmaf(w,x3.y,acc[13]);
      acc[14]=fmaf(w,x3.z,acc[14]); acc[15]=fmaf(w,x3.w,acc[15]);
    }
    #pragma unroll
    for (int k=0;k<16;++k)
      EW[((size_t)b*TT + t0 + k)*320 + tid] = acc[k];
  }
}

__global__ __launch_bounds__(BT) void decoder_kernel(Pr P){
  const int blk = blockIdx.x, tid = threadIdx.x;
  const int sq = blk & 15, coh = blk >> 4;     // blk%8 = sq%8 -> slice pinned per XCD
  const int b0 = coh * 4;
  unsigned* ctr = P.ctr + coh*64;

  __shared__ float4 hj4[512];
  __shared__ float4 pj4[DD];
  __shared__ float4 h1j4[DD];
  __shared__ float4 h2j4[DD];
  __shared__ float4 qs4[32];
  __shared__ float4 ctx4[32];
  __shared__ float4 l2a4[320];
  __shared__ float4 scr4[2048];   // [0..512) transient; [512..2048) GRU h-partials (persist)
  __shared__ float  awb[4][1024];
  __shared__ float  c1s[4][80], c2s[4][80];
  __shared__ float  pv[4][16], msta[4][8], mscl[4][8], mwt[4][8];
  __shared__ float  stp[320];
  __shared__ int    wlo[4], whi[4];

  float* hjF=(float*)hj4;  float* pjF=(float*)pj4;  float* h1F=(float*)h1j4;
  float* h2F=(float*)h2j4; float* scrF=(float*)scr4; float* qsF=(float*)qs4;

  { float4 z{};
    for (int i=tid;i<512;i+=BT) hj4[i]=z;
    for (int i=tid;i<1536;i+=BT) scr4[512+i]=z;   // h-partials for step 0 (h(-1)=0)
    if (tid<DD){ h1j4[tid]=z; h2j4[tid]=z; }
    if (tid<320){ c1s[tid&3][tid>>2]=0.f; c2s[tid&3][tid>>2]=0.f; }
    if (tid<32) msta[tid>>3][tid&7]=0.f;
  }
  // zero all 3 accumulator parities for own batch range
  if (tid<320){
    #pragma unroll
    for (int par=0;par<3;++par)
      #pragma unroll
      for (int g=0;g<4;++g)
        gstore(&P.pls[par*20480 + (size_t)(b0+g)*320 + tid], 0.f);
  }
  if (tid<64){
    #pragma unroll
    for (int par=0;par<3;++par)
      gstore(&P.pp[par*1024 + (size_t)(b0 + (tid>>4))*16 + (tid&15)], 0.f);
  }
  unsigned tgt = 16;
  cbar_arrive(ctr); cbar_wait(ctr, tgt);     // init barrier (zeros durable)

  for (int l=0; l<LL; ++l){
    float* plA = P.pls + (l%3)*20480;        // add (P3) + read (post-C) this step
    float* plZ = P.pls + ((l+1)%3)*20480;    // zeroed pre-C for step l+1
    float* ppA = P.pp  + (l%3)*1024;         // add (P2) + read (post-B) this step
    float* ppZ = P.pp  + ((l+1)%3)*1024;     // zeroed pre-C for step l+1
    const int wr = l & 15;                   // rotating writer slice

    // ===== P0: prenet (h2 of step l-1) =====
    if (tid<320){
      const int col=tid>>2, g=tid&3;
      float s=P.pb1[col];
      #pragma unroll 4
      for (int j=0;j<DD;++j) s = fmaf(h2F[j*4+g], P.pW1[j*DD+col], s);
      scrF[col*4+g]=fmaxf(s,0.f);
    }
    __syncthreads();
    if (tid<320){
      const int col=tid>>2, g=tid&3;
      float s=P.pb2[col];
      #pragma unroll 4
      for (int j=0;j<DD;++j) s = fmaf(scrF[j*4+g], P.pW2[j*DD+col], s);
      pjF[col*4+g]=fmaxf(s,0.f);
    }
    __syncthreads();

    // ===== P1': GRU p-part only (h-part precomputed in B/C shadows of step l-1) =====
    if (tid<128){
      const int u = tid & 31, psl = tid >> 5;   // 4 slices x 20 rows
      const int cb = sq*32 + u;
      float4 ar{}, az{}, axn{};
      const int j0 = psl*20;
      #pragma unroll 4
      for (int jj=0;jj<20;++jj){
        const int j = j0+jj;
        float4 x = pj4[j];
        const float* W = P.gWx + (size_t)j*1536 + cb;
        acc4(ar,W[0],x); acc4(az,W[512],x); acc4(axn,W[1024],x);
      }
      scr4[0*128 + psl*32+u]=ar;
      scr4[1*128 + psl*32+u]=az;
      scr4[2*128 + psl*32+u]=axn;
    }
    __syncthreads();
    if (tid<128){                        // fused reduce (4 p-slices + 16 h-slices) + publish
      const int u=tid>>2, g=tid&3, uu=sq*32+u;
      float rx=0,zx=0,xn=0,hn=0;
      #pragma unroll
      for (int k=0;k<4;++k){
        rx += scrF[(0*128+k*32+u)*4+g];
        zx += scrF[(1*128+k*32+u)*4+g];
        xn += scrF[(2*128+k*32+u)*4+g];
      }
      #pragma unroll
      for (int k=0;k<16;++k){
        rx += scrF[(512 + 0*512 + k*32+u)*4+g];
        zx += scrF[(512 + 1*512 + k*32+u)*4+g];
        hn += scrF[(512 + 2*512 + k*32+u)*4+g];
      }
      float r = sigm(rx + P.gbx[uu] + P.gbh[uu]);
      float z = sigm(zx + P.gbx[512+uu] + P.gbh[512+uu]);
      float n = tanhf(xn + P.gbx[1024+uu] + r*(hn + P.gbh[1024+uu]));
      float ho = (1.f-z)*n + z*hjF[uu*4+g];
      gstore(&P.hb[(size_t)(b0+g)*512 + uu], ho);
    }
    cbar_arrive(ctr);                    // ---- A arrive
    if (tid<320){                        // A-shadow: LSTM2 h2-part (h2 = l-1)
      float4 a{};
      const float* W = P.lWh2 + tid;
      #pragma unroll 4
      for (int j=0;j<DD;++j) acc4(a, W[(size_t)j*320], h2j4[j]);
      l2a4[tid]=a;
    }
    cbar_wait(ctr, tgt);                 // ---- A wait
    {
      float4 h;
      h.x=gload(&P.hb[(size_t)(b0+0)*512+tid]);
      h.y=gload(&P.hb[(size_t)(b0+1)*512+tid]);
      h.z=gload(&P.hb[(size_t)(b0+2)*512+tid]);
      h.w=gload(&P.hb[(size_t)(b0+3)*512+tid]);
      hj4[tid]=h;
    }
    __syncthreads();

    // ===== P2: q slice (32 cols) + param partials =====
    {
      const int c = tid & 31, jsl = tid >> 5, j0 = jsl*32;
      float4 a{};
      const float* W = P.aW1 + (size_t)j0*512 + sq*32 + c;
      #pragma unroll 4
      for (int jj=0;jj<32;++jj) acc4(a, W[(size_t)jj*512], hj4[j0+jj]);
      scr4[jsl*32+c]=a;
    }
    __syncthreads();
    if (tid<128){
      const int c=tid>>2, g=tid&3;
      float s=0.f;
      #pragma unroll
      for (int k=0;k<16;++k) s += scrF[(k*32+c)*4+g];
      qsF[c*4+g] = tanhf(s + P.ab1[sq*32+c]);
    }
    __syncthreads();
    if (tid<60){
      const int col=tid%15, g=tid/15;
      float s=0.f;
      #pragma unroll 4
      for (int j=0;j<32;++j) s = fmaf(qsF[j*4+g], P.aW2[(size_t)(sq*32+j)*15+col], s);
      gadd(&ppA[(size_t)(b0+g)*16 + col], s);
    }
    cbar_arrive(ctr);                    // ---- B arrive
    // B-shadow: LSTM1 h-part + h1-part, plus GRU(l+1) h-rows 0..11 (hj4 = h(l))
    float4 l1acc{};
    float4 g_ar{}, g_az{}, g_ahn{};
    const int gu = tid & 31, ghsl = tid >> 5;
    const int gcb = sq*32 + gu, gh0 = ghsl*32;
    if (tid<320){
      { const float* W = P.lWx1 + (size_t)(512+sq*32)*320 + tid;
        #pragma unroll 4
        for (int j=0;j<32;++j) acc4(l1acc, W[(size_t)j*320], hj4[sq*32+j]); }
      { const float* W = P.lWh1 + (size_t)(sq*5)*320 + tid;
        #pragma unroll
        for (int j=0;j<5;++j)  acc4(l1acc, W[(size_t)j*320], h1j4[sq*5+j]); }
    }
    {
      #pragma unroll 4
      for (int jj=0;jj<12;++jj){
        float4 x = hj4[gh0+jj];
        const float* W = P.gWh + (size_t)(gh0+jj)*1536 + gcb;
        acc4(g_ar,W[0],x); acc4(g_az,W[512],x); acc4(g_ahn,W[1024],x);
      }
    }
    cbar_wait(ctr, tgt);                 // ---- B wait
    if (tid<60){
      const int col=tid%15, g=tid/15;
      pv[g][col] = gload(&ppA[(size_t)(b0+g)*16 + col]) + P.ab2[col];
    }
    __syncthreads();
    if (tid<4){
      const int g=tid;
      float lo=3.4e38f, hi=-3.4e38f, mmax=-3.4e38f;
      #pragma unroll
      for (int k=0;k<KK;++k){
        float m = msta[g][k] + softplusf(pv[g][k]);
        msta[g][k]=m;
        float sc = softplusf(pv[g][5+k]) + 1e-4f;
        mscl[g][k]=sc;
        mmax = fmaxf(mmax, pv[g][10+k]);
        lo = fminf(lo, m-0.5f-16.f*sc);  // e^-16 tail: mass < 2e-7 (abs err ~1e-6)
        hi = fmaxf(hi, m+0.5f+16.f*sc);
      }
      float den=0.f;
      #pragma unroll
      for (int k=0;k<KK;++k){ float e=expf(pv[g][10+k]-mmax); mwt[g][k]=e; den+=e; }
      float rd=1.f/den;
      #pragma unroll
      for (int k=0;k<KK;++k) mwt[g][k]*=rd;
      int ilo=(int)fmaxf(0.f,floorf(lo));
      int ihi=(int)fminf((float)TT,ceilf(hi)+1.f);
      if (ihi<ilo) ihi=ilo;
      wlo[g]=ilo; whi[g]=ihi;
    }
    __syncthreads();

    // ===== P3: attention-weighted x-part =====
    if (P.useEW){
      { const int g = tid>>7, lane = tid&127;
        const int lo_=wlo[g], hi_=whi[g];
        for (int t = lo_+lane; t < hi_; t += 128){
          const float tf=(float)t;
          float s=0.f;
          #pragma unroll
          for (int k=0;k<KK;++k){
            float mu=msta[g][k], sc=mscl[g][k];
            s += mwt[g][k]*(sigm((tf+0.5f-mu)/sc)-sigm((tf-0.5f-mu)/sc));
          }
          awb[g][t-lo_]=s;
        }
      }
      __syncthreads();
      if (tid<320){
        float* lp=(float*)&l1acc;
        const float* EWb = P.ew;
        #pragma unroll
        for (int g=0;g<4;++g){
          const int lo_=wlo[g], hi_=whi[g];
          for (int t=lo_+sq; t<hi_; t+=16)
            lp[g] = fmaf(awb[g][t-lo_], EWb[((size_t)(b0+g)*TT+t)*320+tid], lp[g]);
        }
      }
    } else {
      { const int eq = tid&7, g = (tid>>3)&3, ts = tid>>5;
        const float* bz = P.enc + (size_t)(b0+g)*TT*EE + sq*32 + eq*4;
        float4 acc{};
        for (int t = wlo[g]+ts; t < whi[g]; t += 16){
          const float tf=(float)t;
          float awv=0.f;
          #pragma unroll
          for (int k=0;k<KK;++k){
            float mu=msta[g][k], sc=mscl[g][k];
            awv += mwt[g][k]*(sigm((tf+0.5f-mu)/sc)-sigm((tf-0.5f-mu)/sc));
          }
          float4 v = *(const float4*)(bz+(size_t)t*EE);
          acc.x=fmaf(awv,v.x,acc.x); acc.y=fmaf(awv,v.y,acc.y);
          acc.z=fmaf(awv,v.z,acc.z); acc.w=fmaf(awv,v.w,acc.w);
        }
        ((float4*)scrF)[ts*32 + g*8 + eq]=acc;
      }
      __syncthreads();
      if (tid<128){
        const int g=tid>>5, e=tid&31;
        float s=0.f;
        #pragma unroll
        for (int k=0;k<16;++k) s += scrF[(k*32 + g*8 + (e>>2))*4 + (e&3)];
        ((float*)&ctx4[e])[g]=s;
      }
      __syncthreads();
      if (tid<320){
        const float* W = P.lWx1 + (size_t)(sq*32)*320 + tid;
        #pragma unroll 4
        for (int j=0;j<32;++j) acc4(l1acc, W[(size_t)j*320], ctx4[j]);
      }
    }
    if (tid<320){                        // publish LSTM1 partials via LLC atomicAdd
      float* lp=(float*)&l1acc;
      #pragma unroll
      for (int g=0;g<4;++g) gadd(&plA[(size_t)(b0+g)*320 + tid], lp[g]);
    }
    // pre-C distributed zeroing of NEXT-step accumulators (spare / writer threads)
    if (tid>=384 && tid<464){            // pl: own 20-col slice x 4 g
      const int t2=tid-384, c=sq*20+(t2>>2), g=t2&3;
      gstore(&plZ[(size_t)(b0+g)*320 + c], 0.f);
    }
    if (sq==wr && tid>=320 && tid<380){  // pp: writer block, 15 cols x 4 g
      const int t2=tid-320, col=t2%15, g=t2/15;
      gstore(&ppZ[(size_t)(b0+g)*16 + col], 0.f);
    }
    cbar_arrive(ctr);                    // ---- C arrive (adds + zeros durable)
    {                                    // C-shadow: GRU(l+1) h-rows 12..31
      #pragma unroll 4
      for (int jj=12;jj<32;++jj){
        float4 x = hj4[gh0+jj];
        const float* W = P.gWh + (size_t)(gh0+jj)*1536 + gcb;
        acc4(g_ar,W[0],x); acc4(g_az,W[512],x); acc4(g_ahn,W[1024],x);
      }
      scr4[512 + 0*512 + ghsl*32+gu]=g_ar;
      scr4[512 + 1*512 + ghsl*32+gu]=g_az;
      scr4[512 + 2*512 + ghsl*32+gu]=g_ahn;
    }
    cbar_wait(ctr, tgt);                 // ---- C wait
    if (tid<320){                        // 4-load readback (READ ONLY) + h1/c1 update
      const int u=tid>>2, g=tid&3;
      float gate[4];
      #pragma unroll
      for (int gg=0;gg<4;++gg)
        gate[gg] = gload(&plA[(size_t)(b0+g)*320 + gg*80 + u]) + P.lb1[gg*80+u];
      float i_=sigm(gate[0]), f_=sigm(gate[1]), g_=tanhf(gate[2]), o_=sigm(gate[3]);
      float cn=f_*c1s[g][u]+i_*g_;
      c1s[g][u]=cn;
      h1F[u*4+g]=o_*tanhf(cn);
    }
    __syncthreads();
    if (tid<320){                        // LSTM2 x-part + gates (h2-part from A-shadow)
      float4 a = l2a4[tid];
      const float* W = P.lWx2 + tid;
      #pragma unroll 4
      for (int j=0;j<DD;++j) acc4(a, W[(size_t)j*320], h1j4[j]);
      const float bb=P.lb2[tid];
      a.x+=bb; a.y+=bb; a.z+=bb; a.w+=bb;
      scr4[tid]=a;
    }
    __syncthreads();
    if (tid<320){                        // c2/h2 update + outputs (rotating writer)
      const int u=tid>>2, g=tid&3;
      float i_=sigm(scrF[(0*80+u)*4+g]);
      float f_=sigm(scrF[(1*80+u)*4+g]);
      float g_=tanhf(scrF[(2*80+u)*4+g]);
      float o_=sigm(scrF[(3*80+u)*4+g]);
      float cn=f_*c2s[g][u]+i_*g_;
      c2s[g][u]=cn;
      float hn=o_*tanhf(cn);
      h2F[u*4+g]=hn;
      stp[u*4+g]=hn*P.sW[u];
      if (sq==wr){
        const size_t o=((size_t)(b0+g)*LL+l)*DD+u;
        P.oa[o]=hn; P.obf[o]=hn;
      }
    }
    __syncthreads();
    if (tid<4 && sq==wr){                // stop logit (straggles into next P0 safely)
      float s=P.sb[0];
      for (int u=0;u<DD;++u) s+=stp[u*4+tid];
      P.ol[(size_t)(b0+tid)*LL+l]=s;
    }
  }
}

extern "C" void kernel_launch(void* const* d_in, const int* in_sizes, int n_in,
                              void* d_out, int out_size, void* d_ws, size_t ws_size,
                              hipStream_t stream){
  (void)in_sizes; (void)n_in; (void)out_size;
  if (ws_size < (size_t)WF_EW*sizeof(float)) return;
  const int useEW = ws_size >= (size_t)(WF_EW + WF_EWSZ)*sizeof(float);

  hipMemsetAsync(d_ws, 0, 8192, stream);   // zero cohort barrier counters

  Pr P;
  P.enc = (const float*)d_in[0];
  P.pW1=(const float*)d_in[2];  P.pb1=(const float*)d_in[3];
  P.pW2=(const float*)d_in[4];  P.pb2=(const float*)d_in[5];
  P.gWx=(const float*)d_in[6];  P.gWh=(const float*)d_in[7];
  P.gbx=(const float*)d_in[8];  P.gbh=(const float*)d_in[9];
  P.aW1=(const float*)d_in[10]; P.ab1=(const float*)d_in[11];
  P.aW2=(const float*)d_in[12]; P.ab2=(const float*)d_in[13];
  P.lWx1=(const float*)d_in[14]; P.lWh1=(const float*)d_in[15]; P.lb1=(const float*)d_in[16];
  P.lWx2=(const float*)d_in[17]; P.lWh2=(const float*)d_in[18]; P.lb2=(const float*)d_in[19];
  P.sW=(const float*)d_in[20];  P.sb=(const float*)d_in[21];

  float* ws = (float*)d_ws;
  P.ctr = (unsigned*)ws;           // [0..2048) u32
  P.hb  = ws + WF_HB;              // [64][512]
  P.pp  = ws + WF_PP;              // [3][64][16]
  P.pls = ws + WF_PL;              // [3][64][320]
  P.ew  = ws + WF_EW;
  P.useEW = useEW;

  if (useEW)
    ew_kernel<<<dim3(BB, TT/16), 512, 0, stream>>>(P.enc, P.lWx1, P.ew);

  float* o = (float*)d_out;
  P.oa  = o;
  P.obf = o + (size_t)BB*LL*DD;
  P.ol  = o + (size_t)2*BB*LL*DD;

  void* args[] = { (void*)&P };
  hipLaunchCooperativeKernel((void*)decoder_kernel, dim3(NB), dim3(BT), args, 0, stream);
}

// Round 18
// 10712.723 us; speedup vs baseline: 1.0162x; 1.0162x over previous
//
#include <hip/hip_runtime.h>

#define NB 256      // 16 cohorts x 16 slice-blocks
#define BT 512
#define BB 64
#define TT 1024
#define LL 400
#define EE 512
#define DD 80
#define AA 512
#define KK 5

// ws float offsets
#define WF_HB 2048                    // [64][512] hout exchange
#define WF_PP 34816                   // [3][64][16] param partial accumulators
#define WF_PL 51200                   // [3][64][320] lstm1 partial accumulators
#define WF_EW 112640                  // [64][1024][320] enc@Wx1 (optional)
#define WF_EWSZ (64UL*1024UL*320UL)

struct Pr {
  const float *enc;
  const float *pW1,*pb1,*pW2,*pb2;
  const float *gWx,*gWh,*gbx,*gbh;
  const float *aW1,*ab1,*aW2,*ab2;
  const float *lWx1,*lWh1,*lb1,*lWx2,*lWh2,*lb2;
  const float *sW,*sb;
  float *oa,*obf,*ol;
  unsigned *ctr;
  float *hb,*pp,*pls,*ew;
  int useEW;
};

__device__ __forceinline__ float sigm(float x){ return 1.f/(1.f+expf(-x)); }
__device__ __forceinline__ float softplusf(float x){ return fmaxf(x,0.f)+log1pf(expf(-fabsf(x))); }
__device__ __forceinline__ void gstore(float* p, float v){
  __hip_atomic_store(p, v, __ATOMIC_RELAXED, __HIP_MEMORY_SCOPE_AGENT);
}
__device__ __forceinline__ float gload(const float* p){
  return __hip_atomic_load(p, __ATOMIC_RELAXED, __HIP_MEMORY_SCOPE_AGENT);
}
__device__ __forceinline__ void gadd(float* p, float v){
  __hip_atomic_fetch_add(p, v, __ATOMIC_RELAXED, __HIP_MEMORY_SCOPE_AGENT);
}
__device__ __forceinline__ void acc4(float4& a, float w, const float4 x){
  a.x = fmaf(w,x.x,a.x); a.y = fmaf(w,x.y,a.y);
  a.z = fmaf(w,x.z,a.z); a.w = fmaf(w,x.w,a.w);
}

// 16-block cohort barrier, split arrive/wait (fence-free; proven r5-r17)
__device__ __forceinline__ void cbar_arrive(unsigned* ctr){
  __syncthreads();
  if (threadIdx.x == 0){
    asm volatile("s_waitcnt vmcnt(0)" ::: "memory");
    __hip_atomic_fetch_add(ctr, 1u, __ATOMIC_RELAXED, __HIP_MEMORY_SCOPE_AGENT);
  }
}
__device__ __forceinline__ void cbar_wait(unsigned* ctr, unsigned& tgt){
  if (threadIdx.x == 0){
    while (__hip_atomic_load(ctr, __ATOMIC_RELAXED, __HIP_MEMORY_SCOPE_AGENT) < tgt)
      __builtin_amdgcn_s_sleep(1);
  }
  __syncthreads();
  tgt += 16;
}

// one-time EW[b][t][col] = sum_e enc[b][t][e] * lWx1[e][col]
__global__ __launch_bounds__(512) void ew_kernel(const float* __restrict__ enc,
                                                 const float* __restrict__ W,
                                                 float* __restrict__ EW){
  const int b = blockIdx.x, t0 = blockIdx.y*16, tid = threadIdx.x;
  __shared__ float encT[512*16];
  #pragma unroll
  for (int r=0;r<16;++r)
    encT[tid*16+r] = enc[((size_t)b*TT + t0 + r)*EE + tid];
  __syncthreads();
  if (tid < 320){
    float acc[16];
    #pragma unroll
    for (int k=0;k<16;++k) acc[k]=0.f;
    const float* wp = W + tid;
    #pragma unroll 2
    for (int e=0;e<512;++e){
      float w = wp[(size_t)e*320];
      const float4* er = (const float4*)&encT[e*16];
      float4 x0=er[0], x1=er[1], x2=er[2], x3=er[3];
      acc[0]=fmaf(w,x0.x,acc[0]); acc[1]=fmaf(w,x0.y,acc[1]);
      acc[2]=fmaf(w,x0.z,acc[2]); acc[3]=fmaf(w,x0.w,acc[3]);
      acc[4]=fmaf(w,x1.x,acc[4]); acc[5]=fmaf(w,x1.y,acc[5]);
      acc[6]=fmaf(w,x1.z,acc[6]); acc[7]=fmaf(w,x1.w,acc[7]);
      acc[8]=fmaf(w,x2.x,acc[8]); acc[9]=fmaf(w,x2.y,acc[9]);
      acc[10]=fmaf(w,x2.z,acc[10]); acc[11]=fmaf(w,x2.w,acc[11]);
      acc[12]=fmaf(w,x3.x,acc[12]); acc[13]=fmaf(w,x3.y,acc[13]);
      acc[14]=fmaf(w,x3.z,acc[14]); acc[15]=fmaf(w,x3.w,acc[15]);
    }
    #pragma unroll
    for (int k=0;k<16;++k)
      EW[((size_t)b*TT + t0 + k)*320 + tid] = acc[k];
  }
}

__global__ __launch_bounds__(BT) void decoder_kernel(Pr P){
  const int blk = blockIdx.x, tid = threadIdx.x;
  const int sq = blk & 15, coh = blk >> 4;     // blk%8 = sq%8 -> slice pinned per XCD
  const int b0 = coh * 4;
  unsigned* ctr = P.ctr + coh*64;

  __shared__ float4 hj4[512];
  __shared__ float4 pj4[DD];
  __shared__ float4 h1j4[DD];
  __shared__ float4 h2j4[DD];
  __shared__ float4 qs4[32];
  __shared__ float4 ctx4[32];
  __shared__ float4 l2a4[320];
  __shared__ float4 scr4[2048];   // [0..512) transient; [512..2048) GRU h-partials (persist)
  __shared__ float  awb[4][1024];
  __shared__ float  c1s[4][80], c2s[4][80];
  __shared__ float  pv[4][16], msta[4][8], mscl[4][8], mwt[4][8];
  __shared__ float  stp[320];
  __shared__ int    wlo[4], whi[4];

  float* hjF=(float*)hj4;  float* pjF=(float*)pj4;  float* h1F=(float*)h1j4;
  float* h2F=(float*)h2j4; float* scrF=(float*)scr4; float* qsF=(float*)qs4;

  { float4 z{};
    for (int i=tid;i<512;i+=BT) hj4[i]=z;
    for (int i=tid;i<1536;i+=BT) scr4[512+i]=z;   // h-partials for step 0 (h(-1)=0)
    if (tid<DD){ h1j4[tid]=z; h2j4[tid]=z; }
    if (tid<320){ c1s[tid&3][tid>>2]=0.f; c2s[tid&3][tid>>2]=0.f; }
    if (tid<32) msta[tid>>3][tid&7]=0.f;
  }
  // zero all 3 accumulator parities for own batch range
  if (tid<320){
    #pragma unroll
    for (int par=0;par<3;++par)
      #pragma unroll
      for (int g=0;g<4;++g)
        gstore(&P.pls[par*20480 + (size_t)(b0+g)*320 + tid], 0.f);
  }
  if (tid<64){
    #pragma unroll
    for (int par=0;par<3;++par)
      gstore(&P.pp[par*1024 + (size_t)(b0 + (tid>>4))*16 + (tid&15)], 0.f);
  }
  unsigned tgt = 16;
  cbar_arrive(ctr); cbar_wait(ctr, tgt);     // init barrier (zeros durable)

  for (int l=0; l<LL; ++l){
    float* plA = P.pls + (l%3)*20480;        // add (P3) + read (post-C) this step
    float* plZ = P.pls + ((l+1)%3)*20480;    // zeroed post-C for step l+1
    float* ppA = P.pp  + (l%3)*1024;         // add (P2) + read (post-B) this step
    float* ppZ = P.pp  + ((l+1)%3)*1024;     // zeroed pre-C for step l+1
    const int wr = l & 15;                   // rotating writer slice

    // ===== P0: prenet (h2 of step l-1) =====
    if (tid<320){
      const int col=tid>>2, g=tid&3;
      float s=P.pb1[col];
      #pragma unroll 4
      for (int j=0;j<DD;++j) s = fmaf(h2F[j*4+g], P.pW1[j*DD+col], s);
      scrF[col*4+g]=fmaxf(s,0.f);
    }
    __syncthreads();
    if (tid<320){
      const int col=tid>>2, g=tid&3;
      float s=P.pb2[col];
      #pragma unroll 4
      for (int j=0;j<DD;++j) s = fmaf(scrF[j*4+g], P.pW2[j*DD+col], s);
      pjF[col*4+g]=fmaxf(s,0.f);
    }
    __syncthreads();

    // ===== P1': GRU p-part only (h-part precomputed in C-shadow of step l-1) =====
    if (tid<128){
      const int u = tid & 31, psl = tid >> 5;   // 4 slices x 20 rows
      const int cb = sq*32 + u;
      float4 ar{}, az{}, axn{};
      const int j0 = psl*20;
      #pragma unroll 4
      for (int jj=0;jj<20;++jj){
        const int j = j0+jj;
        float4 x = pj4[j];
        const float* W = P.gWx + (size_t)j*1536 + cb;
        acc4(ar,W[0],x); acc4(az,W[512],x); acc4(axn,W[1024],x);
      }
      scr4[0*128 + psl*32+u]=ar;
      scr4[1*128 + psl*32+u]=az;
      scr4[2*128 + psl*32+u]=axn;
    }
    __syncthreads();
    if (tid<128){                        // fused reduce (4 p-slices + 16 h-slices) + publish
      const int u=tid>>2, g=tid&3, uu=sq*32+u;
      float rx=0,zx=0,xn=0,hn=0;
      #pragma unroll
      for (int k=0;k<4;++k){
        rx += scrF[(0*128+k*32+u)*4+g];
        zx += scrF[(1*128+k*32+u)*4+g];
        xn += scrF[(2*128+k*32+u)*4+g];
      }
      #pragma unroll
      for (int k=0;k<16;++k){
        rx += scrF[(512 + 0*512 + k*32+u)*4+g];
        zx += scrF[(512 + 1*512 + k*32+u)*4+g];
        hn += scrF[(512 + 2*512 + k*32+u)*4+g];
      }
      float r = sigm(rx + P.gbx[uu] + P.gbh[uu]);
      float z = sigm(zx + P.gbx[512+uu] + P.gbh[512+uu]);
      float n = tanhf(xn + P.gbx[1024+uu] + r*(hn + P.gbh[1024+uu]));
      float ho = (1.f-z)*n + z*hjF[uu*4+g];
      gstore(&P.hb[(size_t)(b0+g)*512 + uu], ho);
    }
    cbar_arrive(ctr);                    // ---- A arrive
    if (tid<320){                        // A-shadow: LSTM2 h2-part (h2 = l-1)
      float4 a{};
      const float* W = P.lWh2 + tid;
      #pragma unroll 4
      for (int j=0;j<DD;++j) acc4(a, W[(size_t)j*320], h2j4[j]);
      l2a4[tid]=a;
    }
    cbar_wait(ctr, tgt);                 // ---- A wait
    {
      float4 h;
      h.x=gload(&P.hb[(size_t)(b0+0)*512+tid]);
      h.y=gload(&P.hb[(size_t)(b0+1)*512+tid]);
      h.z=gload(&P.hb[(size_t)(b0+2)*512+tid]);
      h.w=gload(&P.hb[(size_t)(b0+3)*512+tid]);
      hj4[tid]=h;
    }
    __syncthreads();

    // ===== P2: q slice (32 cols) + param partials (LLC atomicAdd) =====
    {
      const int c = tid & 31, jsl = tid >> 5, j0 = jsl*32;
      float4 a{};
      const float* W = P.aW1 + (size_t)j0*512 + sq*32 + c;
      #pragma unroll 4
      for (int jj=0;jj<32;++jj) acc4(a, W[(size_t)jj*512], hj4[j0+jj]);
      scr4[jsl*32+c]=a;
    }
    __syncthreads();
    if (tid<128){
      const int c=tid>>2, g=tid&3;
      float s=0.f;
      #pragma unroll
      for (int k=0;k<16;++k) s += scrF[(k*32+c)*4+g];
      qsF[c*4+g] = tanhf(s + P.ab1[sq*32+c]);
    }
    __syncthreads();
    if (tid<60){
      const int col=tid%15, g=tid/15;
      float s=0.f;
      #pragma unroll 4
      for (int j=0;j<32;++j) s = fmaf(qsF[j*4+g], P.aW2[(size_t)(sq*32+j)*15+col], s);
      gadd(&ppA[(size_t)(b0+g)*16 + col], s);
    }
    cbar_arrive(ctr);                    // ---- B arrive
    float4 l1acc{};                      // B-shadow: LSTM1 h-part + h1-part
    if (tid<320){
      { const float* W = P.lWx1 + (size_t)(512+sq*32)*320 + tid;
        #pragma unroll 4
        for (int j=0;j<32;++j) acc4(l1acc, W[(size_t)j*320], hj4[sq*32+j]); }
      { const float* W = P.lWh1 + (size_t)(sq*5)*320 + tid;
        #pragma unroll
        for (int j=0;j<5;++j)  acc4(l1acc, W[(size_t)j*320], h1j4[sq*5+j]); }
    }
    cbar_wait(ctr, tgt);                 // ---- B wait
    if (tid<60){
      const int col=tid%15, g=tid/15;
      pv[g][col] = gload(&ppA[(size_t)(b0+g)*16 + col]) + P.ab2[col];
    }
    __syncthreads();
    if (tid<4){
      const int g=tid;
      float lo=3.4e38f, hi=-3.4e38f, mmax=-3.4e38f;
      #pragma unroll
      for (int k=0;k<KK;++k){
        float m = msta[g][k] + softplusf(pv[g][k]);
        msta[g][k]=m;
        float sc = softplusf(pv[g][5+k]) + 1e-4f;
        mscl[g][k]=sc;
        mmax = fmaxf(mmax, pv[g][10+k]);
        lo = fminf(lo, m-0.5f-12.f*sc);  // e^-12 tail: mass < 7e-6 (abs err ~1e-5)
        hi = fmaxf(hi, m+0.5f+12.f*sc);
      }
      float den=0.f;
      #pragma unroll
      for (int k=0;k<KK;++k){ float e=expf(pv[g][10+k]-mmax); mwt[g][k]=e; den+=e; }
      float rd=1.f/den;
      #pragma unroll
      for (int k=0;k<KK;++k) mwt[g][k]*=rd;
      int ilo=(int)fmaxf(0.f,floorf(lo));
      int ihi=(int)fminf((float)TT,ceilf(hi)+1.f);
      if (ihi<ilo) ihi=ilo;
      wlo[g]=ilo; whi[g]=ihi;
    }
    __syncthreads();

    // ===== P3: attention-weighted x-part =====
    if (P.useEW){
      { const int g = tid>>7, lane = tid&127;
        const int lo_=wlo[g], hi_=whi[g];
        for (int t = lo_+lane; t < hi_; t += 128){
          const float tf=(float)t;
          float s=0.f;
          #pragma unroll
          for (int k=0;k<KK;++k){
            float mu=msta[g][k], sc=mscl[g][k];
            s += mwt[g][k]*(sigm((tf+0.5f-mu)/sc)-sigm((tf-0.5f-mu)/sc));
          }
          awb[g][t-lo_]=s;
        }
      }
      __syncthreads();
      if (tid<320){
        float* lp=(float*)&l1acc;
        const float* EWb = P.ew;
        #pragma unroll
        for (int g=0;g<4;++g){
          const int lo_=wlo[g], hi_=whi[g];
          for (int t=lo_+sq; t<hi_; t+=16)
            lp[g] = fmaf(awb[g][t-lo_], EWb[((size_t)(b0+g)*TT+t)*320+tid], lp[g]);
        }
      }
    } else {
      { const int eq = tid&7, g = (tid>>3)&3, ts = tid>>5;
        const float* bz = P.enc + (size_t)(b0+g)*TT*EE + sq*32 + eq*4;
        float4 acc{};
        for (int t = wlo[g]+ts; t < whi[g]; t += 16){
          const float tf=(float)t;
          float awv=0.f;
          #pragma unroll
          for (int k=0;k<KK;++k){
            float mu=msta[g][k], sc=mscl[g][k];
            awv += mwt[g][k]*(sigm((tf+0.5f-mu)/sc)-sigm((tf-0.5f-mu)/sc));
          }
          float4 v = *(const float4*)(bz+(size_t)t*EE);
          acc.x=fmaf(awv,v.x,acc.x); acc.y=fmaf(awv,v.y,acc.y);
          acc.z=fmaf(awv,v.z,acc.z); acc.w=fmaf(awv,v.w,acc.w);
        }
        ((float4*)scrF)[ts*32 + g*8 + eq]=acc;
      }
      __syncthreads();
      if (tid<128){
        const int g=tid>>5, e=tid&31;
        float s=0.f;
        #pragma unroll
        for (int k=0;k<16;++k) s += scrF[(k*32 + g*8 + (e>>2))*4 + (e&3)];
        ((float*)&ctx4[e])[g]=s;
      }
      __syncthreads();
      if (tid<320){
        const float* W = P.lWx1 + (size_t)(sq*32)*320 + tid;
        #pragma unroll 4
        for (int j=0;j<32;++j) acc4(l1acc, W[(size_t)j*320], ctx4[j]);
      }
    }
    if (tid<320){                        // publish LSTM1 partials via LLC atomicAdd
      float* lp=(float*)&l1acc;
      #pragma unroll
      for (int g=0;g<4;++g) gadd(&plA[(size_t)(b0+g)*320 + tid], lp[g]);
    }
    if (sq==wr && tid>=320 && tid<380){  // pre-C: zero NEXT-step pp buffer (writer block)
      const int t2=tid-320, col=t2%15, g=t2/15;
      gstore(&ppZ[(size_t)(b0+g)*16 + col], 0.f);
    }
    cbar_arrive(ctr);                    // ---- C arrive (adds + pp zeros durable)
    {                                    // C-shadow: NEXT-step GRU h-part (hj4 = h(l))
      const int u = tid & 31, hsl = tid >> 5;   // 16 slices x 32 rows
      const int cb = sq*32 + u;
      float4 ar{}, az{}, ahn{};
      const int h0 = hsl*32;
      #pragma unroll 4
      for (int jj=0;jj<32;++jj){
        float4 x = hj4[h0+jj];
        const float* W = P.gWh + (size_t)(h0+jj)*1536 + cb;
        acc4(ar,W[0],x); acc4(az,W[512],x); acc4(ahn,W[1024],x);
      }
      scr4[512 + 0*512 + hsl*32+u]=ar;
      scr4[512 + 1*512 + hsl*32+u]=az;
      scr4[512 + 2*512 + hsl*32+u]=ahn;
    }
    cbar_wait(ctr, tgt);                 // ---- C wait
    if (tid<320){                        // 4-load readback (READ ONLY) + h1/c1 update
      const int u=tid>>2, g=tid&3;
      float gate[4];
      #pragma unroll
      for (int gg=0;gg<4;++gg)
        gate[gg] = gload(&plA[(size_t)(b0+g)*320 + gg*80 + u]) + P.lb1[gg*80+u];
      float i_=sigm(gate[0]), f_=sigm(gate[1]), g_=tanhf(gate[2]), o_=sigm(gate[3]);
      float cn=f_*c1s[g][u]+i_*g_;
      c1s[g][u]=cn;
      h1F[u*4+g]=o_*tanhf(cn);
    }
    if (sq==wr && tid<320){              // zero NEXT-step pl buffer (rotating writer);
      #pragma unroll                     // durable before l+1's adds via A-barrier of l+1
      for (int g=0;g<4;++g) gstore(&plZ[(size_t)(b0+g)*320 + tid], 0.f);
    }
    __syncthreads();
    if (tid<320){                        // LSTM2 x-part + gates (h2-part from A-shadow)
      float4 a = l2a4[tid];
      const float* W = P.lWx2 + tid;
      #pragma unroll 4
      for (int j=0;j<DD;++j) acc4(a, W[(size_t)j*320], h1j4[j]);
      const float bb=P.lb2[tid];
      a.x+=bb; a.y+=bb; a.z+=bb; a.w+=bb;
      scr4[tid]=a;
    }
    __syncthreads();
    if (tid<320){                        // c2/h2 update + outputs (rotating writer)
      const int u=tid>>2, g=tid&3;
      float i_=sigm(scrF[(0*80+u)*4+g]);
      float f_=sigm(scrF[(1*80+u)*4+g]);
      float g_=tanhf(scrF[(2*80+u)*4+g]);
      float o_=sigm(scrF[(3*80+u)*4+g]);
      float cn=f_*c2s[g][u]+i_*g_;
      c2s[g][u]=cn;
      float hn=o_*tanhf(cn);
      h2F[u*4+g]=hn;
      stp[u*4+g]=hn*P.sW[u];
      if (sq==wr){
        const size_t o=((size_t)(b0+g)*LL+l)*DD+u;
        P.oa[o]=hn; P.obf[o]=hn;
      }
    }
    __syncthreads();
    if (tid<4 && sq==wr){                // stop logit (straggles into next P0 safely)
      float s=P.sb[0];
      for (int u=0;u<DD;++u) s+=stp[u*4+tid];
      P.ol[(size_t)(b0+tid)*LL+l]=s;
    }
  }
}

extern "C" void kernel_launch(void* const* d_in, const int* in_sizes, int n_in,
                              void* d_out, int out_size, void* d_ws, size_t ws_size,
                              hipStream_t stream){
  (void)in_sizes; (void)n_in; (void)out_size;
  if (ws_size < (size_t)WF_EW*sizeof(float)) return;
  const int useEW = ws_size >= (size_t)(WF_EW + WF_EWSZ)*sizeof(float);

  hipMemsetAsync(d_ws, 0, 8192, stream);   // zero cohort barrier counters

  Pr P;
  P.enc = (const float*)d_in[0];
  P.pW1=(const float*)d_in[2];  P.pb1=(const float*)d_in[3];
  P.pW2=(const float*)d_in[4];  P.pb2=(const float*)d_in[5];
  P.gWx=(const float*)d_in[6];  P.gWh=(const float*)d_in[7];
  P.gbx=(const float*)d_in[8];  P.gbh=(const float*)d_in[9];
  P.aW1=(const float*)d_in[10]; P.ab1=(const float*)d_in[11];
  P.aW2=(const float*)d_in[12]; P.ab2=(const float*)d_in[13];
  P.lWx1=(const float*)d_in[14]; P.lWh1=(const float*)d_in[15]; P.lb1=(const float*)d_in[16];
  P.lWx2=(const float*)d_in[17]; P.lWh2=(const float*)d_in[18]; P.lb2=(const float*)d_in[19];
  P.sW=(const float*)d_in[20];  P.sb=(const float*)d_in[21];

  float* ws = (float*)d_ws;
  P.ctr = (unsigned*)ws;           // [0..2048) u32
  P.hb  = ws + WF_HB;              // [64][512]
  P.pp  = ws + WF_PP;              // [3][64][16]
  P.pls = ws + WF_PL;              // [3][64][320]
  P.ew  = ws + WF_EW;
  P.useEW = useEW;

  if (useEW)
    ew_kernel<<<dim3(BB, TT/16), 512, 0, stream>>>(P.enc, P.lWx1, P.ew);

  float* o = (float*)d_out;
  P.oa  = o;
  P.obf = o + (size_t)BB*LL*DD;
  P.ol  = o + (size_t)2*BB*LL*DD;

  void* args[] = { (void*)&P };
  hipLaunchCooperativeKernel((void*)decoder_kernel, dim3(NB), dim3(BT), args, 0, stream);
}

// Round 19
// 10031.817 us; speedup vs baseline: 1.0852x; 1.0679x over previous
//
#include <hip/hip_runtime.h>

#define NB 256      // 16 cohorts x 16 slice-blocks
#define BT 512
#define BB 64
#define TT 1024
#define LL 400
#define EE 512
#define DD 80
#define AA 512
#define KK 5

// ws float offsets
#define WF_HB 2048                    // [64][512] hout exchange
#define WF_PP 34816                   // [3][64][16] param partial accumulators
#define WF_PL 51200                   // [3][64][320] lstm1 partial accumulators
#define WF_EW 112640                  // [64][1024][320] enc@Wx1 (optional)
#define WF_EWSZ (64UL*1024UL*320UL)

struct Pr {
  const float *enc;
  const float *pW1,*pb1,*pW2,*pb2;
  const float *gWx,*gWh,*gbx,*gbh;
  const float *aW1,*ab1,*aW2,*ab2;
  const float *lWx1,*lWh1,*lb1,*lWx2,*lWh2,*lb2;
  const float *sW,*sb;
  float *oa,*obf,*ol;
  unsigned *ctr;
  float *hb,*pp,*pls,*ew;
  int useEW;
};

__device__ __forceinline__ float sigm(float x){ return 1.f/(1.f+expf(-x)); }
__device__ __forceinline__ float softplusf(float x){ return fmaxf(x,0.f)+log1pf(expf(-fabsf(x))); }
__device__ __forceinline__ void gstore(float* p, float v){
  __hip_atomic_store(p, v, __ATOMIC_RELAXED, __HIP_MEMORY_SCOPE_AGENT);
}
__device__ __forceinline__ float gload(const float* p){
  return __hip_atomic_load(p, __ATOMIC_RELAXED, __HIP_MEMORY_SCOPE_AGENT);
}
__device__ __forceinline__ void gadd(float* p, float v){
  __hip_atomic_fetch_add(p, v, __ATOMIC_RELAXED, __HIP_MEMORY_SCOPE_AGENT);
}
__device__ __forceinline__ void acc4(float4& a, float w, const float4 x){
  a.x = fmaf(w,x.x,a.x); a.y = fmaf(w,x.y,a.y);
  a.z = fmaf(w,x.z,a.z); a.w = fmaf(w,x.w,a.w);
}

// 16-block cohort barrier, split arrive/wait (fence-free; proven r5-r18)
__device__ __forceinline__ void cbar_arrive(unsigned* ctr){
  __syncthreads();
  if (threadIdx.x == 0){
    asm volatile("s_waitcnt vmcnt(0)" ::: "memory");
    __hip_atomic_fetch_add(ctr, 1u, __ATOMIC_RELAXED, __HIP_MEMORY_SCOPE_AGENT);
  }
}
__device__ __forceinline__ void cbar_wait(unsigned* ctr, unsigned& tgt){
  if (threadIdx.x == 0){
    while (__hip_atomic_load(ctr, __ATOMIC_RELAXED, __HIP_MEMORY_SCOPE_AGENT) < tgt)
      __builtin_amdgcn_s_sleep(1);
  }
  __syncthreads();
  tgt += 16;
}

// one-time EW[b][t][col] = sum_e enc[b][t][e] * lWx1[e][col]
__global__ __launch_bounds__(512) void ew_kernel(const float* __restrict__ enc,
                                                 const float* __restrict__ W,
                                                 float* __restrict__ EW){
  const int b = blockIdx.x, t0 = blockIdx.y*16, tid = threadIdx.x;
  __shared__ float encT[512*16];
  #pragma unroll
  for (int r=0;r<16;++r)
    encT[tid*16+r] = enc[((size_t)b*TT + t0 + r)*EE + tid];
  __syncthreads();
  if (tid < 320){
    float acc[16];
    #pragma unroll
    for (int k=0;k<16;++k) acc[k]=0.f;
    const float* wp = W + tid;
    #pragma unroll 2
    for (int e=0;e<512;++e){
      float w = wp[(size_t)e*320];
      const float4* er = (const float4*)&encT[e*16];
      float4 x0=er[0], x1=er[1], x2=er[2], x3=er[3];
      acc[0]=fmaf(w,x0.x,acc[0]); acc[1]=fmaf(w,x0.y,acc[1]);
      acc[2]=fmaf(w,x0.z,acc[2]); acc[3]=fmaf(w,x0.w,acc[3]);
      acc[4]=fmaf(w,x1.x,acc[4]); acc[5]=fmaf(w,x1.y,acc[5]);
      acc[6]=fmaf(w,x1.z,acc[6]); acc[7]=fmaf(w,x1.w,acc[7]);
      acc[8]=fmaf(w,x2.x,acc[8]); acc[9]=fmaf(w,x2.y,acc[9]);
      acc[10]=fmaf(w,x2.z,acc[10]); acc[11]=fmaf(w,x2.w,acc[11]);
      acc[12]=fmaf(w,x3.x,acc[12]); acc[13]=fmaf(w,x3.y,acc[13]);
      acc[14]=fmaf(w,x3.z,acc[14]); acc[15]=fmaf(w,x3.w,acc[15]);
    }
    #pragma unroll
    for (int k=0;k<16;++k)
      EW[((size_t)b*TT + t0 + k)*320 + tid] = acc[k];
  }
}

__global__ __launch_bounds__(BT) void decoder_kernel(Pr P){
  const int blk = blockIdx.x, tid = threadIdx.x;
  const int sq = blk & 15, coh = blk >> 4;     // blk%8 = sq%8 -> slice pinned per XCD
  const int b0 = coh * 4;
  unsigned* ctr = P.ctr + coh*64;

  __shared__ float4 hj4[512];
  __shared__ float4 pj4[DD];
  __shared__ float4 h1j4[DD];
  __shared__ float4 h2j4[DD];
  __shared__ float4 qs4[32];
  __shared__ float4 ctx4[32];
  __shared__ float4 l2a4[320];
  __shared__ float4 scr4[2048];   // [0..512) transient; [512..2048) GRU h-partials (persist)
  __shared__ float  awb[4][1024];
  __shared__ float  c1s[4][80], c2s[4][80];
  __shared__ float  msta[4][8], mscl[4][8], mwt[4][8];
  __shared__ float  stp[320];
  __shared__ int    wlo[4], whi[4];

  float* hjF=(float*)hj4;  float* pjF=(float*)pj4;  float* h1F=(float*)h1j4;
  float* h2F=(float*)h2j4; float* scrF=(float*)scr4; float* qsF=(float*)qs4;

  { float4 z{};
    for (int i=tid;i<512;i+=BT) hj4[i]=z;
    for (int i=tid;i<1536;i+=BT) scr4[512+i]=z;   // h-partials for step 0 (h(-1)=0)
    if (tid<DD){ h1j4[tid]=z; h2j4[tid]=z; }
    if (tid<320){ c1s[tid&3][tid>>2]=0.f; c2s[tid&3][tid>>2]=0.f; }
    if (tid<32) msta[tid>>3][tid&7]=0.f;
  }
  // zero all 3 accumulator parities for own batch range
  if (tid<320){
    #pragma unroll
    for (int par=0;par<3;++par)
      #pragma unroll
      for (int g=0;g<4;++g)
        gstore(&P.pls[par*20480 + (size_t)(b0+g)*320 + tid], 0.f);
  }
  if (tid<64){
    #pragma unroll
    for (int par=0;par<3;++par)
      gstore(&P.pp[par*1024 + (size_t)(b0 + (tid>>4))*16 + (tid&15)], 0.f);
  }
  unsigned tgt = 16;
  cbar_arrive(ctr); cbar_wait(ctr, tgt);     // init barrier (zeros durable)

  for (int l=0; l<LL; ++l){
    float* plA = P.pls + (l%3)*20480;        // add (P3) + read (post-C) this step
    float* plZ = P.pls + ((l+1)%3)*20480;    // zeroed post-C (distributed) for step l+1
    float* ppA = P.pp  + (l%3)*1024;         // add (P2) + read (post-B) this step
    float* ppZ = P.pp  + ((l+1)%3)*1024;     // zeroed pre-C for step l+1
    const int wr = l & 15;                   // rotating writer slice

    // ===== P0: prenet (h2 of step l-1) =====
    if (tid<320){
      const int col=tid>>2, g=tid&3;
      float s=P.pb1[col];
      #pragma unroll 4
      for (int j=0;j<DD;++j) s = fmaf(h2F[j*4+g], P.pW1[j*DD+col], s);
      scrF[col*4+g]=fmaxf(s,0.f);
    }
    __syncthreads();
    if (tid<320){
      const int col=tid>>2, g=tid&3;
      float s=P.pb2[col];
      #pragma unroll 4
      for (int j=0;j<DD;++j) s = fmaf(scrF[j*4+g], P.pW2[j*DD+col], s);
      pjF[col*4+g]=fmaxf(s,0.f);
    }
    __syncthreads();

    // ===== P1': GRU p-part only (h-part precomputed in C-shadow of step l-1) =====
    if (tid<128){
      const int u = tid & 31, psl = tid >> 5;   // 4 slices x 20 rows
      const int cb = sq*32 + u;
      float4 ar{}, az{}, axn{};
      const int j0 = psl*20;
      #pragma unroll 4
      for (int jj=0;jj<20;++jj){
        const int j = j0+jj;
        float4 x = pj4[j];
        const float* W = P.gWx + (size_t)j*1536 + cb;
        acc4(ar,W[0],x); acc4(az,W[512],x); acc4(axn,W[1024],x);
      }
      scr4[0*128 + psl*32+u]=ar;
      scr4[1*128 + psl*32+u]=az;
      scr4[2*128 + psl*32+u]=axn;
    }
    __syncthreads();
    if (tid<128){                        // fused reduce (4 p-slices + 16 h-slices) + publish
      const int u=tid>>2, g=tid&3, uu=sq*32+u;
      float rx=0,zx=0,xn=0,hn=0;
      #pragma unroll
      for (int k=0;k<4;++k){
        rx += scrF[(0*128+k*32+u)*4+g];
        zx += scrF[(1*128+k*32+u)*4+g];
        xn += scrF[(2*128+k*32+u)*4+g];
      }
      #pragma unroll
      for (int k=0;k<16;++k){
        rx += scrF[(512 + 0*512 + k*32+u)*4+g];
        zx += scrF[(512 + 1*512 + k*32+u)*4+g];
        hn += scrF[(512 + 2*512 + k*32+u)*4+g];
      }
      float r = sigm(rx + P.gbx[uu] + P.gbh[uu]);
      float z = sigm(zx + P.gbx[512+uu] + P.gbh[512+uu]);
      float n = tanhf(xn + P.gbx[1024+uu] + r*(hn + P.gbh[1024+uu]));
      float ho = (1.f-z)*n + z*hjF[uu*4+g];
      gstore(&P.hb[(size_t)(b0+g)*512 + uu], ho);
    }
    cbar_arrive(ctr);                    // ---- A arrive
    if (tid<320){                        // A-shadow: LSTM2 h2-part (h2 = l-1)
      float4 a{};
      const float* W = P.lWh2 + tid;
      #pragma unroll 4
      for (int j=0;j<DD;++j) acc4(a, W[(size_t)j*320], h2j4[j]);
      l2a4[tid]=a;
    }
    cbar_wait(ctr, tgt);                 // ---- A wait
    {
      float4 h;
      h.x=gload(&P.hb[(size_t)(b0+0)*512+tid]);
      h.y=gload(&P.hb[(size_t)(b0+1)*512+tid]);
      h.z=gload(&P.hb[(size_t)(b0+2)*512+tid]);
      h.w=gload(&P.hb[(size_t)(b0+3)*512+tid]);
      hj4[tid]=h;
    }
    __syncthreads();

    // ===== P2: q slice (32 cols) + param partials (LLC atomicAdd) =====
    {
      const int c = tid & 31, jsl = tid >> 5, j0 = jsl*32;
      float4 a{};
      const float* W = P.aW1 + (size_t)j0*512 + sq*32 + c;
      #pragma unroll 4
      for (int jj=0;jj<32;++jj) acc4(a, W[(size_t)jj*512], hj4[j0+jj]);
      scr4[jsl*32+c]=a;
    }
    __syncthreads();
    if (tid<128){
      const int c=tid>>2, g=tid&3;
      float s=0.f;
      #pragma unroll
      for (int k=0;k<16;++k) s += scrF[(k*32+c)*4+g];
      qsF[c*4+g] = tanhf(s + P.ab1[sq*32+c]);
    }
    __syncthreads();
    if (tid<60){
      const int col=tid%15, g=tid/15;
      float s=0.f;
      #pragma unroll 4
      for (int j=0;j<32;++j) s = fmaf(qsF[j*4+g], P.aW2[(size_t)(sq*32+j)*15+col], s);
      gadd(&ppA[(size_t)(b0+g)*16 + col], s);
    }
    cbar_arrive(ctr);                    // ---- B arrive
    float4 l1acc{};                      // B-shadow: LSTM1 h-part + h1-part
    if (tid<320){
      { const float* W = P.lWx1 + (size_t)(512+sq*32)*320 + tid;
        #pragma unroll 4
        for (int j=0;j<32;++j) acc4(l1acc, W[(size_t)j*320], hj4[sq*32+j]); }
      { const float* W = P.lWh1 + (size_t)(sq*5)*320 + tid;
        #pragma unroll
        for (int j=0;j<5;++j)  acc4(l1acc, W[(size_t)j*320], h1j4[sq*5+j]); }
    }
    cbar_wait(ctr, tgt);                 // ---- B wait
    // wave-0 fused mixture: parallel pv load + transcendentals, shfl 5-lane reductions
    if (tid<20){
      const int g=tid/5, k=tid-5*(tid/5);
      const float* pb = &ppA[(size_t)(b0+g)*16];
      float av = gload(pb+k)    + P.ab2[k];
      float bv = gload(pb+5+k)  + P.ab2[5+k];
      float cv = gload(pb+10+k) + P.ab2[10+k];
      float m  = msta[g][k] + softplusf(av);
      float sc = softplusf(bv) + 1e-4f;
      float e  = expf(cv);               // no max-sub: |logit| <= ~18, exp safe
      float lok = m-0.5f-12.f*sc;        // e^-12 tail: mass < 7e-6 (abs err ~1e-5)
      float hik = m+0.5f+12.f*sc;
      float den=0.f, lo=3.4e38f, hi=-3.4e38f;
      #pragma unroll
      for (int j=0;j<5;++j){             // fixed order j=0..4: identical across lanes/blocks
        den += __shfl(e,   g*5+j);
        lo  = fminf(lo, __shfl(lok, g*5+j));
        hi  = fmaxf(hi, __shfl(hik, g*5+j));
      }
      msta[g][k]=m; mscl[g][k]=sc; mwt[g][k]=e/den;
      if (k==0){
        int ilo=(int)fmaxf(0.f,floorf(lo));
        int ihi=(int)fminf((float)TT,ceilf(hi)+1.f);
        if (ihi<ilo) ihi=ilo;
        wlo[g]=ilo; whi[g]=ihi;
      }
    }
    __syncthreads();

    // ===== P3: attention-weighted x-part =====
    if (P.useEW){
      { const int g = tid>>7, lane = tid&127;
        const int lo_=wlo[g], hi_=whi[g];
        for (int t = lo_+lane; t < hi_; t += 128){
          const float tf=(float)t;
          float s=0.f;
          #pragma unroll
          for (int k=0;k<KK;++k){
            float mu=msta[g][k], sc=mscl[g][k];
            s += mwt[g][k]*(sigm((tf+0.5f-mu)/sc)-sigm((tf-0.5f-mu)/sc));
          }
          awb[g][t-lo_]=s;
        }
      }
      __syncthreads();
      if (tid<320){
        float* lp=(float*)&l1acc;
        const float* EWb = P.ew;
        #pragma unroll
        for (int g=0;g<4;++g){
          const int lo_=wlo[g], hi_=whi[g];
          for (int t=lo_+sq; t<hi_; t+=16)
            lp[g] = fmaf(awb[g][t-lo_], EWb[((size_t)(b0+g)*TT+t)*320+tid], lp[g]);
        }
      }
    } else {
      { const int eq = tid&7, g = (tid>>3)&3, ts = tid>>5;
        const float* bz = P.enc + (size_t)(b0+g)*TT*EE + sq*32 + eq*4;
        float4 acc{};
        for (int t = wlo[g]+ts; t < whi[g]; t += 16){
          const float tf=(float)t;
          float awv=0.f;
          #pragma unroll
          for (int k=0;k<KK;++k){
            float mu=msta[g][k], sc=mscl[g][k];
            awv += mwt[g][k]*(sigm((tf+0.5f-mu)/sc)-sigm((tf-0.5f-mu)/sc));
          }
          float4 v = *(const float4*)(bz+(size_t)t*EE);
          acc.x=fmaf(awv,v.x,acc.x); acc.y=fmaf(awv,v.y,acc.y);
          acc.z=fmaf(awv,v.z,acc.z); acc.w=fmaf(awv,v.w,acc.w);
        }
        ((float4*)scrF)[ts*32 + g*8 + eq]=acc;
      }
      __syncthreads();
      if (tid<128){
        const int g=tid>>5, e=tid&31;
        float s=0.f;
        #pragma unroll
        for (int k=0;k<16;++k) s += scrF[(k*32 + g*8 + (e>>2))*4 + (e&3)];
        ((float*)&ctx4[e])[g]=s;
      }
      __syncthreads();
      if (tid<320){
        const float* W = P.lWx1 + (size_t)(sq*32)*320 + tid;
        #pragma unroll 4
        for (int j=0;j<32;++j) acc4(l1acc, W[(size_t)j*320], ctx4[j]);
      }
    }
    if (tid<320){                        // publish LSTM1 partials via LLC atomicAdd
      float* lp=(float*)&l1acc;
      #pragma unroll
      for (int g=0;g<4;++g) gadd(&plA[(size_t)(b0+g)*320 + tid], lp[g]);
    }
    if (sq==wr && tid>=320 && tid<380){  // pre-C: zero NEXT-step pp buffer (writer block)
      const int t2=tid-320, col=t2%15, g=t2/15;
      gstore(&ppZ[(size_t)(b0+g)*16 + col], 0.f);
    }
    cbar_arrive(ctr);                    // ---- C arrive (adds + pp zeros durable)
    {                                    // C-shadow: NEXT-step GRU h-part (hj4 = h(l))
      const int u = tid & 31, hsl = tid >> 5;   // 16 slices x 32 rows
      const int cb = sq*32 + u;
      float4 ar{}, az{}, ahn{};
      const int h0 = hsl*32;
      #pragma unroll 4
      for (int jj=0;jj<32;++jj){
        float4 x = hj4[h0+jj];
        const float* W = P.gWh + (size_t)(h0+jj)*1536 + cb;
        acc4(ar,W[0],x); acc4(az,W[512],x); acc4(ahn,W[1024],x);
      }
      scr4[512 + 0*512 + hsl*32+u]=ar;
      scr4[512 + 1*512 + hsl*32+u]=az;
      scr4[512 + 2*512 + hsl*32+u]=ahn;
    }
    cbar_wait(ctr, tgt);                 // ---- C wait
    if (tid<320){                        // 4-load readback (READ ONLY) + h1/c1 update
      const int u=tid>>2, g=tid&3;
      float gate[4];
      #pragma unroll
      for (int gg=0;gg<4;++gg)
        gate[gg] = gload(&plA[(size_t)(b0+g)*320 + gg*80 + u]) + P.lb1[gg*80+u];
      float i_=sigm(gate[0]), f_=sigm(gate[1]), g_=tanhf(gate[2]), o_=sigm(gate[3]);
      float cn=f_*c1s[g][u]+i_*g_;
      c1s[g][u]=cn;
      h1F[u*4+g]=o_*tanhf(cn);
    }
    if (tid>=384 && tid<464){            // distributed zero of NEXT-step pl buffer
      const int t2=tid-384, c=sq*20+(t2>>2), g=t2&3;   // (spare threads, all blocks;
      gstore(&plZ[(size_t)(b0+g)*320 + c], 0.f);       //  durable at next A-arrive)
    }
    __syncthreads();
    if (tid<320){                        // LSTM2 x-part + gates (h2-part from A-shadow)
      float4 a = l2a4[tid];
      const float* W = P.lWx2 + tid;
      #pragma unroll 4
      for (int j=0;j<DD;++j) acc4(a, W[(size_t)j*320], h1j4[j]);
      const float bb=P.lb2[tid];
      a.x+=bb; a.y+=bb; a.z+=bb; a.w+=bb;
      scr4[tid]=a;
    }
    __syncthreads();
    if (tid<320){                        // c2/h2 update + outputs (rotating writer)
      const int u=tid>>2, g=tid&3;
      float i_=sigm(scrF[(0*80+u)*4+g]);
      float f_=sigm(scrF[(1*80+u)*4+g]);
      float g_=tanhf(scrF[(2*80+u)*4+g]);
      float o_=sigm(scrF[(3*80+u)*4+g]);
      float cn=f_*c2s[g][u]+i_*g_;
      c2s[g][u]=cn;
      float hn=o_*tanhf(cn);
      h2F[u*4+g]=hn;
      stp[u*4+g]=hn*P.sW[u];
      if (sq==wr){
        const size_t o=((size_t)(b0+g)*LL+l)*DD+u;
        P.oa[o]=hn; P.obf[o]=hn;
      }
    }
    __syncthreads();
    if (tid<4 && sq==wr){                // stop logit (straggles into next P0 safely)
      float s=P.sb[0];
      for (int u=0;u<DD;++u) s+=stp[u*4+tid];
      P.ol[(size_t)(b0+tid)*LL+l]=s;
    }
  }
}

extern "C" void kernel_launch(void* const* d_in, const int* in_sizes, int n_in,
                              void* d_out, int out_size, void* d_ws, size_t ws_size,
                              hipStream_t stream){
  (void)in_sizes; (void)n_in; (void)out_size;
  if (ws_size < (size_t)WF_EW*sizeof(float)) return;
  const int useEW = ws_size >= (size_t)(WF_EW + WF_EWSZ)*sizeof(float);

  hipMemsetAsync(d_ws, 0, 8192, stream);   // zero cohort barrier counters

  Pr P;
  P.enc = (const float*)d_in[0];
  P.pW1=(const float*)d_in[2];  P.pb1=(const float*)d_in[3];
  P.pW2=(const float*)d_in[4];  P.pb2=(const float*)d_in[5];
  P.gWx=(const float*)d_in[6];  P.gWh=(const float*)d_in[7];
  P.gbx=(const float*)d_in[8];  P.gbh=(const float*)d_in[9];
  P.aW1=(const float*)d_in[10]; P.ab1=(const float*)d_in[11];
  P.aW2=(const float*)d_in[12]; P.ab2=(const float*)d_in[13];
  P.lWx1=(const float*)d_in[14]; P.lWh1=(const float*)d_in[15]; P.lb1=(const float*)d_in[16];
  P.lWx2=(const float*)d_in[17]; P.lWh2=(const float*)d_in[18]; P.lb2=(const float*)d_in[19];
  P.sW=(const float*)d_in[20];  P.sb=(const float*)d_in[21];

  float* ws = (float*)d_ws;
  P.ctr = (unsigned*)ws;           // [0..2048) u32
  P.hb  = ws + WF_HB;              // [64][512]
  P.pp  = ws + WF_PP;              // [3][64][16]
  P.pls = ws + WF_PL;              // [3][64][320]
  P.ew  = ws + WF_EW;
  P.useEW = useEW;

  if (useEW)
    ew_kernel<<<dim3(BB, TT/16), 512, 0, stream>>>(P.enc, P.lWx1, P.ew);

  float* o = (float*)d_out;
  P.oa  = o;
  P.obf = o + (size_t)BB*LL*DD;
  P.ol  = o + (size_t)2*BB*LL*DD;

  void* args[] = { (void*)&P };
  hipLaunchCooperativeKernel((void*)decoder_kernel, dim3(NB), dim3(BT), args, 0, stream);
}

// Round 20
// 10001.408 us; speedup vs baseline: 1.0885x; 1.0030x over previous
//
#include <hip/hip_runtime.h>

#define NB 256      // 16 cohorts x 16 slice-blocks
#define BT 512
#define BB 64
#define TT 1024
#define LL 400
#define EE 512
#define DD 80
#define AA 512
#define KK 5

// ws float offsets
#define WF_HB 2048                    // [64][512] hout exchange
#define WF_PP 34816                   // [3][64][16] param partial accumulators
#define WF_PL 51200                   // [3][64][320] lstm1 partial accumulators
#define WF_EW 112640                  // [64][1024][320] enc@Wx1 (optional)
#define WF_EWSZ (64UL*1024UL*320UL)

struct Pr {
  const float *enc;
  const float *pW1,*pb1,*pW2,*pb2;
  const float *gWx,*gWh,*gbx,*gbh;
  const float *aW1,*ab1,*aW2,*ab2;
  const float *lWx1,*lWh1,*lb1,*lWx2,*lWh2,*lb2;
  const float *sW,*sb;
  float *oa,*obf,*ol;
  unsigned *ctr;
  float *hb,*pp,*pls,*ew;
  int useEW;
};

__device__ __forceinline__ float sigm(float x){ return 1.f/(1.f+expf(-x)); }
__device__ __forceinline__ float softplusf(float x){ return fmaxf(x,0.f)+log1pf(expf(-fabsf(x))); }
__device__ __forceinline__ void gstore(float* p, float v){
  __hip_atomic_store(p, v, __ATOMIC_RELAXED, __HIP_MEMORY_SCOPE_AGENT);
}
__device__ __forceinline__ float gload(const float* p){
  return __hip_atomic_load(p, __ATOMIC_RELAXED, __HIP_MEMORY_SCOPE_AGENT);
}
__device__ __forceinline__ void gadd(float* p, float v){
  __hip_atomic_fetch_add(p, v, __ATOMIC_RELAXED, __HIP_MEMORY_SCOPE_AGENT);
}
__device__ __forceinline__ void acc4(float4& a, float w, const float4 x){
  a.x = fmaf(w,x.x,a.x); a.y = fmaf(w,x.y,a.y);
  a.z = fmaf(w,x.z,a.z); a.w = fmaf(w,x.w,a.w);
}

// 16-block cohort barrier, split arrive/wait (fence-free; proven r5-r19)
__device__ __forceinline__ void cbar_arrive(unsigned* ctr){
  __syncthreads();
  if (threadIdx.x == 0){
    asm volatile("s_waitcnt vmcnt(0)" ::: "memory");
    __hip_atomic_fetch_add(ctr, 1u, __ATOMIC_RELAXED, __HIP_MEMORY_SCOPE_AGENT);
  }
}
__device__ __forceinline__ void cbar_wait(unsigned* ctr, unsigned& tgt){
  if (threadIdx.x == 0){
    while (__hip_atomic_load(ctr, __ATOMIC_RELAXED, __HIP_MEMORY_SCOPE_AGENT) < tgt)
      __builtin_amdgcn_s_sleep(1);
  }
  __syncthreads();
  tgt += 16;
}

// one-time EW[b][t][col] = sum_e enc[b][t][e] * lWx1[e][col]
__global__ __launch_bounds__(512) void ew_kernel(const float* __restrict__ enc,
                                                 const float* __restrict__ W,
                                                 float* __restrict__ EW){
  const int b = blockIdx.x, t0 = blockIdx.y*16, tid = threadIdx.x;
  __shared__ float encT[512*16];
  #pragma unroll
  for (int r=0;r<16;++r)
    encT[tid*16+r] = enc[((size_t)b*TT + t0 + r)*EE + tid];
  __syncthreads();
  if (tid < 320){
    float acc[16];
    #pragma unroll
    for (int k=0;k<16;++k) acc[k]=0.f;
    const float* wp = W + tid;
    #pragma unroll 2
    for (int e=0;e<512;++e){
      float w = wp[(size_t)e*320];
      const float4* er = (const float4*)&encT[e*16];
      float4 x0=er[0], x1=er[1], x2=er[2], x3=er[3];
      acc[0]=fmaf(w,x0.x,acc[0]); acc[1]=fmaf(w,x0.y,acc[1]);
      acc[2]=fmaf(w,x0.z,acc[2]); acc[3]=fmaf(w,x0.w,acc[3]);
      acc[4]=fmaf(w,x1.x,acc[4]); acc[5]=fmaf(w,x1.y,acc[5]);
      acc[6]=fmaf(w,x1.z,acc[6]); acc[7]=fmaf(w,x1.w,acc[7]);
      acc[8]=fmaf(w,x2.x,acc[8]); acc[9]=fmaf(w,x2.y,acc[9]);
      acc[10]=fmaf(w,x2.z,acc[10]); acc[11]=fmaf(w,x2.w,acc[11]);
      acc[12]=fmaf(w,x3.x,acc[12]); acc[13]=fmaf(w,x3.y,acc[13]);
      acc[14]=fmaf(w,x3.z,acc[14]); acc[15]=fmaf(w,x3.w,acc[15]);
    }
    #pragma unroll
    for (int k=0;k<16;++k)
      EW[((size_t)b*TT + t0 + k)*320 + tid] = acc[k];
  }
}

__global__ __launch_bounds__(BT) void decoder_kernel(Pr P){
  const int blk = blockIdx.x, tid = threadIdx.x;
  const int sq = blk & 15, coh = blk >> 4;     // blk%8 = sq%8 -> slice pinned per XCD
  const int b0 = coh * 4;
  unsigned* ctr = P.ctr + coh*64;

  __shared__ float4 hj4[512];
  __shared__ float4 pj4[DD];
  __shared__ float4 h1j4[DD];
  __shared__ float4 h2j4[DD];
  __shared__ float4 qs4[32];
  __shared__ float4 ctx4[32];
  __shared__ float4 l2a4[320];
  __shared__ float4 scr4[2048];   // [0..512) transient; [512..2048) GRU h-partials (persist)
  __shared__ float  awb[4][1024];
  __shared__ float  c1s[4][80], c2s[4][80];
  __shared__ float  msta[4][8], mscl[4][8], mwt[4][8];
  __shared__ float  stp[320];
  __shared__ int    wlo[4], whi[4];

  float* hjF=(float*)hj4;  float* pjF=(float*)pj4;  float* h1F=(float*)h1j4;
  float* h2F=(float*)h2j4; float* scrF=(float*)scr4; float* qsF=(float*)qs4;

  { float4 z{};
    for (int i=tid;i<512;i+=BT) hj4[i]=z;
    for (int i=tid;i<1536;i+=BT) scr4[512+i]=z;   // h-partials for step 0 (h(-1)=0)
    if (tid<DD){ h1j4[tid]=z; h2j4[tid]=z; }
    if (tid<320){ c1s[tid&3][tid>>2]=0.f; c2s[tid&3][tid>>2]=0.f; }
    if (tid<32) msta[tid>>3][tid&7]=0.f;
  }
  // zero all 3 accumulator parities for own batch range
  if (tid<320){
    #pragma unroll
    for (int par=0;par<3;++par)
      #pragma unroll
      for (int g=0;g<4;++g)
        gstore(&P.pls[par*20480 + (size_t)(b0+g)*320 + tid], 0.f);
  }
  if (tid<64){
    #pragma unroll
    for (int par=0;par<3;++par)
      gstore(&P.pp[par*1024 + (size_t)(b0 + (tid>>4))*16 + (tid&15)], 0.f);
  }
  unsigned tgt = 16;
  cbar_arrive(ctr); cbar_wait(ctr, tgt);     // init barrier (zeros durable)

  for (int l=0; l<LL; ++l){
    float* plA = P.pls + (l%3)*20480;        // add (P3) + read (post-C) this step
    float* plZ = P.pls + ((l+1)%3)*20480;    // zeroed post-C (distributed) for step l+1
    float* ppA = P.pp  + (l%3)*1024;         // add (P2) + read (post-B) this step
    float* ppZ = P.pp  + ((l+1)%3)*1024;     // zeroed pre-C for step l+1
    const int wr = l & 15;                   // rotating writer slice

    // ===== P0: prenet (h2 of step l-1) =====
    if (tid<320){
      const int col=tid>>2, g=tid&3;
      float s=P.pb1[col];
      #pragma unroll 4
      for (int j=0;j<DD;++j) s = fmaf(h2F[j*4+g], P.pW1[j*DD+col], s);
      scrF[col*4+g]=fmaxf(s,0.f);
    }
    __syncthreads();
    if (tid<320){
      const int col=tid>>2, g=tid&3;
      float s=P.pb2[col];
      #pragma unroll 4
      for (int j=0;j<DD;++j) s = fmaf(scrF[j*4+g], P.pW2[j*DD+col], s);
      pjF[col*4+g]=fmaxf(s,0.f);
    }
    __syncthreads();

    // ===== P1': GRU p-part only (h-part precomputed in C-shadow of step l-1) =====
    if (tid<128){
      const int u = tid & 31, psl = tid >> 5;   // 4 slices x 20 rows
      const int cb = sq*32 + u;
      float4 ar{}, az{}, axn{};
      const int j0 = psl*20;
      #pragma unroll 4
      for (int jj=0;jj<20;++jj){
        const int j = j0+jj;
        float4 x = pj4[j];
        const float* W = P.gWx + (size_t)j*1536 + cb;
        acc4(ar,W[0],x); acc4(az,W[512],x); acc4(axn,W[1024],x);
      }
      scr4[0*128 + psl*32+u]=ar;
      scr4[1*128 + psl*32+u]=az;
      scr4[2*128 + psl*32+u]=axn;
    }
    __syncthreads();
    if (tid<128){                        // fused reduce (4 p-slices + 16 h-slices) + publish
      const int u=tid>>2, g=tid&3, uu=sq*32+u;
      float rx=0,zx=0,xn=0,hn=0;
      #pragma unroll
      for (int k=0;k<4;++k){
        rx += scrF[(0*128+k*32+u)*4+g];
        zx += scrF[(1*128+k*32+u)*4+g];
        xn += scrF[(2*128+k*32+u)*4+g];
      }
      #pragma unroll
      for (int k=0;k<16;++k){
        rx += scrF[(512 + 0*512 + k*32+u)*4+g];
        zx += scrF[(512 + 1*512 + k*32+u)*4+g];
        hn += scrF[(512 + 2*512 + k*32+u)*4+g];
      }
      float r = sigm(rx + P.gbx[uu] + P.gbh[uu]);
      float z = sigm(zx + P.gbx[512+uu] + P.gbh[512+uu]);
      float n = tanhf(xn + P.gbx[1024+uu] + r*(hn + P.gbh[1024+uu]));
      float ho = (1.f-z)*n + z*hjF[uu*4+g];
      gstore(&P.hb[(size_t)(b0+g)*512 + uu], ho);
    }
    cbar_arrive(ctr);                    // ---- A arrive
    if (tid<320){                        // A-shadow: LSTM2 h2-part (h2 = l-1)
      float4 a{};
      const float* W = P.lWh2 + tid;
      #pragma unroll 4
      for (int j=0;j<DD;++j) acc4(a, W[(size_t)j*320], h2j4[j]);
      l2a4[tid]=a;
    }
    cbar_wait(ctr, tgt);                 // ---- A wait
    {
      float4 h;
      h.x=gload(&P.hb[(size_t)(b0+0)*512+tid]);
      h.y=gload(&P.hb[(size_t)(b0+1)*512+tid]);
      h.z=gload(&P.hb[(size_t)(b0+2)*512+tid]);
      h.w=gload(&P.hb[(size_t)(b0+3)*512+tid]);
      hj4[tid]=h;
    }
    __syncthreads();

    // ===== P2: q slice (32 cols) + param partials (LLC atomicAdd) =====
    {
      const int c = tid & 31, jsl = tid >> 5, j0 = jsl*32;
      float4 a{};
      const float* W = P.aW1 + (size_t)j0*512 + sq*32 + c;
      #pragma unroll 4
      for (int jj=0;jj<32;++jj) acc4(a, W[(size_t)jj*512], hj4[j0+jj]);
      scr4[jsl*32+c]=a;
    }
    __syncthreads();
    if (tid<128){
      const int c=tid>>2, g=tid&3;
      float s=0.f;
      #pragma unroll
      for (int k=0;k<16;++k) s += scrF[(k*32+c)*4+g];
      qsF[c*4+g] = tanhf(s + P.ab1[sq*32+c]);
    }
    __syncthreads();
    if (tid<60){
      const int col=tid%15, g=tid/15;
      float s=0.f;
      #pragma unroll 4
      for (int j=0;j<32;++j) s = fmaf(qsF[j*4+g], P.aW2[(size_t)(sq*32+j)*15+col], s);
      gadd(&ppA[(size_t)(b0+g)*16 + col], s);
    }
    cbar_arrive(ctr);                    // ---- B arrive
    float4 l1acc{};                      // B-shadow: LSTM1 h-part + h1-part
    if (tid<320){
      { const float* W = P.lWx1 + (size_t)(512+sq*32)*320 + tid;
        #pragma unroll 4
        for (int j=0;j<32;++j) acc4(l1acc, W[(size_t)j*320], hj4[sq*32+j]); }
      { const float* W = P.lWh1 + (size_t)(sq*5)*320 + tid;
        #pragma unroll
        for (int j=0;j<5;++j)  acc4(l1acc, W[(size_t)j*320], h1j4[sq*5+j]); }
    }
    cbar_wait(ctr, tgt);                 // ---- B wait
    // wave-0 fused mixture: parallel pv load + transcendentals, shfl 5-lane reductions
    if (tid<20){
      const int g=tid/5, k=tid-5*(tid/5);
      const float* pb = &ppA[(size_t)(b0+g)*16];
      float av = gload(pb+k)    + P.ab2[k];
      float bv = gload(pb+5+k)  + P.ab2[5+k];
      float cv = gload(pb+10+k) + P.ab2[10+k];
      float m  = msta[g][k] + softplusf(av);
      float sc = softplusf(bv) + 1e-4f;
      float e  = expf(cv);               // no max-sub: |logit| <= ~18, exp safe
      float lok = m-0.5f-12.f*sc;        // e^-12 tail: mass < 7e-6 (abs err ~1e-5)
      float hik = m+0.5f+12.f*sc;
      float den=0.f, lo=3.4e38f, hi=-3.4e38f;
      #pragma unroll
      for (int j=0;j<5;++j){             // fixed order j=0..4: identical across lanes/blocks
        den += __shfl(e,   g*5+j);
        lo  = fminf(lo, __shfl(lok, g*5+j));
        hi  = fmaxf(hi, __shfl(hik, g*5+j));
      }
      msta[g][k]=m; mscl[g][k]=sc; mwt[g][k]=e/den;
      if (k==0){
        int ilo=(int)fmaxf(0.f,floorf(lo));
        int ihi=(int)fminf((float)TT,ceilf(hi)+1.f);
        if (ihi<ilo) ihi=ilo;
        wlo[g]=ilo; whi[g]=ihi;
      }
    }
    __syncthreads();

    // ===== P3: attention-weighted x-part =====
    if (P.useEW){
      { const int g = tid>>7, lane = tid&127;
        const int lo_=wlo[g], hi_=whi[g];
        for (int t = lo_+lane; t < hi_; t += 128){
          const float tf=(float)t;
          float s=0.f;
          #pragma unroll
          for (int k=0;k<KK;++k){
            float mu=msta[g][k], sc=mscl[g][k];
            s += mwt[g][k]*(sigm((tf+0.5f-mu)/sc)-sigm((tf-0.5f-mu)/sc));
          }
          awb[g][t-lo_]=s;
        }
      }
      __syncthreads();
      if (tid<320){                      // 4-way interleaved EW accumulation (MLP>=4)
        float* lp=(float*)&l1acc;
        const float* EWb = P.ew;
        const float* eg0 = EWb + ((size_t)(b0+0)*TT)*320 + tid;
        const float* eg1 = EWb + ((size_t)(b0+1)*TT)*320 + tid;
        const float* eg2 = EWb + ((size_t)(b0+2)*TT)*320 + tid;
        const float* eg3 = EWb + ((size_t)(b0+3)*TT)*320 + tid;
        int n = 0;
        #pragma unroll
        for (int g=0;g<4;++g){
          int m = whi[g] - (wlo[g]+sq);
          int ng = (m > 0) ? (m+15)>>4 : 0;
          n = (ng > n) ? ng : n;
        }
        int t0=wlo[0]+sq, t1=wlo[1]+sq, t2=wlo[2]+sq, t3=wlo[3]+sq;
        for (int i=0;i<n;++i){
          if (t0 < whi[0]) lp[0] = fmaf(awb[0][t0-wlo[0]], eg0[(size_t)t0*320], lp[0]);
          if (t1 < whi[1]) lp[1] = fmaf(awb[1][t1-wlo[1]], eg1[(size_t)t1*320], lp[1]);
          if (t2 < whi[2]) lp[2] = fmaf(awb[2][t2-wlo[2]], eg2[(size_t)t2*320], lp[2]);
          if (t3 < whi[3]) lp[3] = fmaf(awb[3][t3-wlo[3]], eg3[(size_t)t3*320], lp[3]);
          t0+=16; t1+=16; t2+=16; t3+=16;
        }
      }
    } else {
      { const int eq = tid&7, g = (tid>>3)&3, ts = tid>>5;
        const float* bz = P.enc + (size_t)(b0+g)*TT*EE + sq*32 + eq*4;
        float4 acc{};
        for (int t = wlo[g]+ts; t < whi[g]; t += 16){
          const float tf=(float)t;
          float awv=0.f;
          #pragma unroll
          for (int k=0;k<KK;++k){
            float mu=msta[g][k], sc=mscl[g][k];
            awv += mwt[g][k]*(sigm((tf+0.5f-mu)/sc)-sigm((tf-0.5f-mu)/sc));
          }
          float4 v = *(const float4*)(bz+(size_t)t*EE);
          acc.x=fmaf(awv,v.x,acc.x); acc.y=fmaf(awv,v.y,acc.y);
          acc.z=fmaf(awv,v.z,acc.z); acc.w=fmaf(awv,v.w,acc.w);
        }
        ((float4*)scrF)[ts*32 + g*8 + eq]=acc;
      }
      __syncthreads();
      if (tid<128){
        const int g=tid>>5, e=tid&31;
        float s=0.f;
        #pragma unroll
        for (int k=0;k<16;++k) s += scrF[(k*32 + g*8 + (e>>2))*4 + (e&3)];
        ((float*)&ctx4[e])[g]=s;
      }
      __syncthreads();
      if (tid<320){
        const float* W = P.lWx1 + (size_t)(sq*32)*320 + tid;
        #pragma unroll 4
        for (int j=0;j<32;++j) acc4(l1acc, W[(size_t)j*320], ctx4[j]);
      }
    }
    if (tid<320){                        // publish LSTM1 partials via LLC atomicAdd
      float* lp=(float*)&l1acc;
      #pragma unroll
      for (int g=0;g<4;++g) gadd(&plA[(size_t)(b0+g)*320 + tid], lp[g]);
    }
    if (sq==wr && tid>=320 && tid<380){  // pre-C: zero NEXT-step pp buffer (writer block)
      const int t2=tid-320, col=t2%15, g=t2/15;
      gstore(&ppZ[(size_t)(b0+g)*16 + col], 0.f);
    }
    cbar_arrive(ctr);                    // ---- C arrive (adds + pp zeros durable)
    {                                    // C-shadow: NEXT-step GRU h-part (hj4 = h(l))
      const int u = tid & 31, hsl = tid >> 5;   // 16 slices x 32 rows
      const int cb = sq*32 + u;
      float4 ar{}, az{}, ahn{};
      const int h0 = hsl*32;
      #pragma unroll 4
      for (int jj=0;jj<32;++jj){
        float4 x = hj4[h0+jj];
        const float* W = P.gWh + (size_t)(h0+jj)*1536 + cb;
        acc4(ar,W[0],x); acc4(az,W[512],x); acc4(ahn,W[1024],x);
      }
      scr4[512 + 0*512 + hsl*32+u]=ar;
      scr4[512 + 1*512 + hsl*32+u]=az;
      scr4[512 + 2*512 + hsl*32+u]=ahn;
    }
    cbar_wait(ctr, tgt);                 // ---- C wait
    if (tid<320){                        // 4-load readback (READ ONLY) + h1/c1 update
      const int u=tid>>2, g=tid&3;
      float gate[4];
      #pragma unroll
      for (int gg=0;gg<4;++gg)
        gate[gg] = gload(&plA[(size_t)(b0+g)*320 + gg*80 + u]) + P.lb1[gg*80+u];
      float i_=sigm(gate[0]), f_=sigm(gate[1]), g_=tanhf(gate[2]), o_=sigm(gate[3]);
      float cn=f_*c1s[g][u]+i_*g_;
      c1s[g][u]=cn;
      h1F[u*4+g]=o_*tanhf(cn);
    }
    if (tid>=384 && tid<464){            // distributed zero of NEXT-step pl buffer
      const int t2=tid-384, c=sq*20+(t2>>2), g=t2&3;   // (spare threads, all blocks;
      gstore(&plZ[(size_t)(b0+g)*320 + c], 0.f);       //  durable at next A-arrive)
    }
    __syncthreads();
    if (tid<320){                        // LSTM2 x-part + gates (h2-part from A-shadow)
      float4 a = l2a4[tid];
      const float* W = P.lWx2 + tid;
      #pragma unroll 4
      for (int j=0;j<DD;++j) acc4(a, W[(size_t)j*320], h1j4[j]);
      const float bb=P.lb2[tid];
      a.x+=bb; a.y+=bb; a.z+=bb; a.w+=bb;
      scr4[tid]=a;
    }
    __syncthreads();
    if (tid<320){                        // c2/h2 update + outputs (rotating writer)
      const int u=tid>>2, g=tid&3;
      float i_=sigm(scrF[(0*80+u)*4+g]);
      float f_=sigm(scrF[(1*80+u)*4+g]);
      float g_=tanhf(scrF[(2*80+u)*4+g]);
      float o_=sigm(scrF[(3*80+u)*4+g]);
      float cn=f_*c2s[g][u]+i_*g_;
      c2s[g][u]=cn;
      float hn=o_*tanhf(cn);
      h2F[u*4+g]=hn;
      stp[u*4+g]=hn*P.sW[u];
      if (sq==wr){
        const size_t o=((size_t)(b0+g)*LL+l)*DD+u;
        P.oa[o]=hn; P.obf[o]=hn;
      }
    }
    __syncthreads();
    if (tid<4 && sq==wr){                // stop logit (straggles into next P0 safely)
      float s=P.sb[0];
      for (int u=0;u<DD;++u) s+=stp[u*4+tid];
      P.ol[(size_t)(b0+tid)*LL+l]=s;
    }
  }
}

extern "C" void kernel_launch(void* const* d_in, const int* in_sizes, int n_in,
                              void* d_out, int out_size, void* d_ws, size_t ws_size,
                              hipStream_t stream){
  (void)in_sizes; (void)n_in; (void)out_size;
  if (ws_size < (size_t)WF_EW*sizeof(float)) return;
  const int useEW = ws_size >= (size_t)(WF_EW + WF_EWSZ)*sizeof(float);

  hipMemsetAsync(d_ws, 0, 8192, stream);   // zero cohort barrier counters

  Pr P;
  P.enc = (const float*)d_in[0];
  P.pW1=(const float*)d_in[2];  P.pb1=(const float*)d_in[3];
  P.pW2=(const float*)d_in[4];  P.pb2=(const float*)d_in[5];
  P.gWx=(const float*)d_in[6];  P.gWh=(const float*)d_in[7];
  P.gbx=(const float*)d_in[8];  P.gbh=(const float*)d_in[9];
  P.aW1=(const float*)d_in[10]; P.ab1=(const float*)d_in[11];
  P.aW2=(const float*)d_in[12]; P.ab2=(const float*)d_in[13];
  P.lWx1=(const float*)d_in[14]; P.lWh1=(const float*)d_in[15]; P.lb1=(const float*)d_in[16];
  P.lWx2=(const float*)d_in[17]; P.lWh2=(const float*)d_in[18]; P.lb2=(const float*)d_in[19];
  P.sW=(const float*)d_in[20];  P.sb=(const float*)d_in[21];

  float* ws = (float*)d_ws;
  P.ctr = (unsigned*)ws;           // [0..2048) u32
  P.hb  = ws + WF_HB;              // [64][512]
  P.pp  = ws + WF_PP;              // [3][64][16]
  P.pls = ws + WF_PL;              // [3][64][320]
  P.ew  = ws + WF_EW;
  P.useEW = useEW;

  if (useEW)
    ew_kernel<<<dim3(BB, TT/16), 512, 0, stream>>>(P.enc, P.lWx1, P.ew);

  float* o = (float*)d_out;
  P.oa  = o;
  P.obf = o + (size_t)BB*LL*DD;
  P.ol  = o + (size_t)2*BB*LL*DD;

  void* args[] = { (void*)&P };
  hipLaunchCooperativeKernel((void*)decoder_kernel, dim3(NB), dim3(BT), args, 0, stream);
}